// Round 1
// baseline (4326.335 us; speedup 1.0000x reference)
//
#include <hip/hip_runtime.h>
#include <hip/hip_bf16.h>

// Problem sizes (fixed)
#define B_SZ 131072
#define F_SZ 784
#define H_SZ 392
#define D_SZ 28
#define K_SZ 512

// Encoder tiling
#define BM 32          // rows per block
#define BK 8           // K-chunk
#define HPAD 465       // padded h row (odd -> conflict-free column reads; also big enough for prior reuse)

// ws layout (float offsets)
//   table   : [512*784]        = 401408
//   pn2     : [512]            @ 401408
//   idxg    : [131072] (int)   @ 401920
//   part1   : [4096]           @ 532992
//   partR   : [2048]           @ 537088
// total 539136 floats = 2.16 MB

// ---------------------------------------------------------------------------
// Precompute decoder table: x_rec_table[k] = relu(prior[k]@W3+b3)@W4 + b4
// and codebook norms pn2[k] = ||prior[k]||^2
// ---------------------------------------------------------------------------
__global__ __launch_bounds__(256) void precompute_kernel(
    const float* __restrict__ W3, const float* __restrict__ b3,
    const float* __restrict__ W4, const float* __restrict__ b4,
    const float* __restrict__ prior,
    float* __restrict__ table, float* __restrict__ pn2) {
  __shared__ float ps[D_SZ];
  __shared__ float h2s[H_SZ];
  const int k = blockIdx.x;
  const int t = threadIdx.x;
  if (t < D_SZ) ps[t] = prior[k * D_SZ + t];
  __syncthreads();
  for (int j = t; j < H_SZ; j += 256) {
    float acc = b3[j];
    #pragma unroll
    for (int d = 0; d < D_SZ; ++d) acc += ps[d] * W3[d * H_SZ + j];
    h2s[j] = fmaxf(acc, 0.f);
  }
  if (t == 0) {
    float s = 0.f;
    #pragma unroll
    for (int d = 0; d < D_SZ; ++d) s += ps[d] * ps[d];
    pn2[k] = s;
  }
  __syncthreads();
  for (int f = t; f < F_SZ; f += 256) {
    float acc = b4[f];
    for (int j = 0; j < H_SZ; ++j) acc += h2s[j] * W4[j * F_SZ + f];
    table[(size_t)k * F_SZ + f] = acc;
  }
}

// ---------------------------------------------------------------------------
// Fused encoder: h = relu(X@W1+b1)  (32x392 per block, f32 tiled GEMM)
//                z = h@W2+b2, argmin_k ||z - prior[k]||^2, loss1 partial
// ---------------------------------------------------------------------------
union EncShared {
  float hs[BM][HPAD];                                // 59,520 B (phase 1-2)
  struct { float p[K_SZ][D_SZ]; float pn[K_SZ]; } dist;  // 59,392 B (phase 3)
};

__global__ __launch_bounds__(256) void encoder_kernel(
    const float* __restrict__ X, const float* __restrict__ W1,
    const float* __restrict__ b1, const float* __restrict__ W2,
    const float* __restrict__ b2, const float* __restrict__ prior,
    const float* __restrict__ pn2, int* __restrict__ idxg,
    float* __restrict__ partial1) {
  __shared__ EncShared S;
  __shared__ float Ws[BK][H_SZ];   // 12,544 B
  __shared__ float Xs[BK][BM];     // 1,024 B ; pos = (r&3)*8 + (r>>2)
  __shared__ float zs[BM][D_SZ];   // 3,584 B
  __shared__ float zn2s[BM];
  __shared__ float red[4];

  const int t = threadIdx.x;
  const int row0 = blockIdx.x * BM;
  const int tr = t >> 6;       // 0..3 row base
  const int tn = t & 63;       // col lane

  // ---- phase 1: GEMM1 ----
  float acc[7][8];
  #pragma unroll
  for (int c = 0; c < 7; ++c)
    #pragma unroll
    for (int rr = 0; rr < 8; ++rr) acc[c][rr] = 0.f;

  for (int k0 = 0; k0 < F_SZ; k0 += BK) {
    __syncthreads();
    if (t < 64) {
      const int r = t >> 1;
      const int kk = (t & 1) * 4;
      const float4 v = *reinterpret_cast<const float4*>(
          &X[(size_t)(row0 + r) * F_SZ + k0 + kk]);
      const int pos = (r & 3) * 8 + (r >> 2);
      Xs[kk + 0][pos] = v.x; Xs[kk + 1][pos] = v.y;
      Xs[kk + 2][pos] = v.z; Xs[kk + 3][pos] = v.w;
    }
    for (int i = t; i < BK * 98; i += 256) {
      const int kk = i / 98;
      const int f4 = i % 98;
      *reinterpret_cast<float4*>(&Ws[kk][f4 * 4]) =
          *reinterpret_cast<const float4*>(&W1[(size_t)(k0 + kk) * H_SZ + f4 * 4]);
    }
    __syncthreads();
    #pragma unroll
    for (int kk = 0; kk < BK; ++kk) {
      float xv[8];
      const float4 a = *reinterpret_cast<const float4*>(&Xs[kk][tr * 8]);
      const float4 b = *reinterpret_cast<const float4*>(&Xs[kk][tr * 8 + 4]);
      xv[0] = a.x; xv[1] = a.y; xv[2] = a.z; xv[3] = a.w;
      xv[4] = b.x; xv[5] = b.y; xv[6] = b.z; xv[7] = b.w;
      #pragma unroll
      for (int c = 0; c < 7; ++c) {
        const int n = tn + 64 * c;
        if (n < H_SZ) {
          const float wv = Ws[kk][n];
          #pragma unroll
          for (int rr = 0; rr < 8; ++rr) acc[c][rr] += xv[rr] * wv;
        }
      }
    }
  }
  // write h tile (relu + bias)
  #pragma unroll
  for (int c = 0; c < 7; ++c) {
    const int n = tn + 64 * c;
    if (n < H_SZ) {
      const float bb = b1[n];
      #pragma unroll
      for (int rr = 0; rr < 8; ++rr)
        S.hs[tr + 4 * rr][n] = fmaxf(acc[c][rr] + bb, 0.f);
    }
  }
  __syncthreads();

  // ---- phase 2: z = h@W2 + b2 ----
  if (t < 224) {
    const int d = t % 28;
    const int rg = t / 28;          // 0..7, rows rg*4 .. rg*4+3
    float za[4];
    #pragma unroll
    for (int i = 0; i < 4; ++i) za[i] = b2[d];
    for (int j = 0; j < H_SZ; ++j) {
      const float w = W2[j * D_SZ + d];
      #pragma unroll
      for (int i = 0; i < 4; ++i) za[i] += S.hs[rg * 4 + i][j] * w;
    }
    #pragma unroll
    for (int i = 0; i < 4; ++i) zs[rg * 4 + i][d] = za[i];
  }
  __syncthreads();
  if (t < BM) {
    float s = 0.f;
    #pragma unroll
    for (int d = 0; d < D_SZ; ++d) s += zs[t][d] * zs[t][d];
    zn2s[t] = s;
  }
  __syncthreads();

  // ---- phase 3: stage prior into LDS (hs is dead), distances + argmin ----
  for (int i = t; i < K_SZ * 7; i += 256) {
    const int k = i / 7, d4 = i % 7;
    *reinterpret_cast<float4*>(&S.dist.p[k][d4 * 4]) =
        *reinterpret_cast<const float4*>(&prior[k * D_SZ + d4 * 4]);
  }
  for (int i = t; i < K_SZ; i += 256) S.dist.pn[i] = pn2[i];
  __syncthreads();

  const int wave = t >> 6;
  const int lane = t & 63;
  float loss1_acc = 0.f;
  for (int rr = 0; rr < 8; ++rr) {
    const int r = wave * 8 + rr;
    float zr[D_SZ];
    #pragma unroll
    for (int d = 0; d < D_SZ; ++d) zr[d] = zs[r][d];
    const float zn2v = zn2s[r];
    float bestv = 3.4028235e38f;
    int besti = 0x7fffffff;
    #pragma unroll
    for (int ki = 0; ki < 8; ++ki) {
      const int k = lane + (ki << 6);
      const float4* pr = reinterpret_cast<const float4*>(&S.dist.p[k][0]);
      float ab = 0.f;
      #pragma unroll
      for (int q = 0; q < 7; ++q) {
        const float4 pv = pr[q];
        ab += zr[q * 4 + 0] * pv.x + zr[q * 4 + 1] * pv.y +
              zr[q * 4 + 2] * pv.z + zr[q * 4 + 3] * pv.w;
      }
      const float dv = fmaxf((zn2v - 2.f * ab) + S.dist.pn[k], 0.f);
      if (dv < bestv) { bestv = dv; besti = k; }  // k ascending: keeps first
    }
    // wave argmin reduce (first-index tie-break, matches jnp.argmin)
    for (int off = 32; off > 0; off >>= 1) {
      const float ov = __shfl_down(bestv, off);
      const int oi = __shfl_down(besti, off);
      if (ov < bestv || (ov == bestv && oi < besti)) { bestv = ov; besti = oi; }
    }
    if (lane == 0) {
      float s = 0.f;
      #pragma unroll
      for (int d = 0; d < D_SZ; ++d) {
        const float df = zr[d] - S.dist.p[besti][d];
        s += df * df;
      }
      loss1_acc += s;
      idxg[row0 + r] = besti;
    }
  }
  if (lane == 0) red[wave] = loss1_acc;
  __syncthreads();
  if (t == 0) partial1[blockIdx.x] = red[0] + red[1] + red[2] + red[3];
}

// ---------------------------------------------------------------------------
// loss_rec: sum over rows of ||x - table[idx]||^2 (re-reads X, table from L2)
// ---------------------------------------------------------------------------
#define R_BLOCKS 2048
#define R_ROWS (B_SZ / R_BLOCKS)  // 64

__global__ __launch_bounds__(256) void rec_kernel(
    const float* __restrict__ X, const float* __restrict__ table,
    const int* __restrict__ idxg, float* __restrict__ partialR) {
  const int t = threadIdx.x;
  const int row0 = blockIdx.x * R_ROWS;
  float acc = 0.f;
  for (int i = t; i < R_ROWS * 196; i += 256) {
    const int rr = i / 196;
    const int f4 = i % 196;
    const int r = row0 + rr;
    const int k = idxg[r];
    const float4 xv = *reinterpret_cast<const float4*>(&X[(size_t)r * F_SZ + f4 * 4]);
    const float4 tv = *reinterpret_cast<const float4*>(&table[(size_t)k * F_SZ + f4 * 4]);
    const float d0 = xv.x - tv.x, d1 = xv.y - tv.y, d2 = xv.z - tv.z, d3 = xv.w - tv.w;
    acc += d0 * d0 + d1 * d1 + d2 * d2 + d3 * d3;
  }
  float v = acc;
  for (int off = 32; off > 0; off >>= 1) v += __shfl_down(v, off);
  __shared__ float rs[4];
  if ((t & 63) == 0) rs[t >> 6] = v;
  __syncthreads();
  if (t == 0) partialR[blockIdx.x] = rs[0] + rs[1] + rs[2] + rs[3];
}

// ---------------------------------------------------------------------------
// Final deterministic reduction: loss = (0.625*s1 + srec)/B
// (loss_1 == loss_2 in forward; 1.25 * 0.5 = 0.625)
// ---------------------------------------------------------------------------
__global__ __launch_bounds__(256) void final_kernel(
    const float* __restrict__ partial1, const float* __restrict__ partialR,
    float* __restrict__ out) {
  __shared__ float s1s[256], srs[256];
  const int t = threadIdx.x;
  float s1 = 0.f, sr = 0.f;
  for (int i = t; i < 4096; i += 256) s1 += partial1[i];
  for (int i = t; i < 2048; i += 256) sr += partialR[i];
  s1s[t] = s1; srs[t] = sr;
  __syncthreads();
  for (int off = 128; off > 0; off >>= 1) {
    if (t < off) { s1s[t] += s1s[t + off]; srs[t] += srs[t + off]; }
    __syncthreads();
  }
  if (t == 0) out[0] = (0.625f * s1s[0] + srs[0]) * (1.0f / (float)B_SZ);
}

extern "C" void kernel_launch(void* const* d_in, const int* in_sizes, int n_in,
                              void* d_out, int out_size, void* d_ws, size_t ws_size,
                              hipStream_t stream) {
  const float* X     = (const float*)d_in[0];
  const float* W1    = (const float*)d_in[1];
  const float* b1    = (const float*)d_in[2];
  const float* W2    = (const float*)d_in[3];
  const float* b2    = (const float*)d_in[4];
  const float* W3    = (const float*)d_in[5];
  const float* b3    = (const float*)d_in[6];
  const float* W4    = (const float*)d_in[7];
  const float* b4    = (const float*)d_in[8];
  const float* prior = (const float*)d_in[9];

  float* wsf   = (float*)d_ws;
  float* table = wsf;
  float* pn2   = wsf + 401408;
  int*   idxg  = (int*)(wsf + 401920);
  float* part1 = wsf + 532992;
  float* partR = wsf + 537088;
  float* out   = (float*)d_out;

  precompute_kernel<<<dim3(512), dim3(256), 0, stream>>>(W3, b3, W4, b4, prior, table, pn2);
  encoder_kernel<<<dim3(B_SZ / BM), dim3(256), 0, stream>>>(X, W1, b1, W2, b2, prior, pn2, idxg, part1);
  rec_kernel<<<dim3(R_BLOCKS), dim3(256), 0, stream>>>(X, table, idxg, partR);
  final_kernel<<<dim3(1), dim3(256), 0, stream>>>(part1, partR, out);
}

// Round 2
// 390.858 us; speedup vs baseline: 11.0688x; 11.0688x over previous
//
#include <hip/hip_runtime.h>
#include <hip/hip_bf16.h>

// Problem sizes (fixed)
#define B_SZ 131072
#define F_SZ 784
#define H_SZ 392
#define D_SZ 28
#define K_SZ 512

typedef __attribute__((ext_vector_type(8))) short short8v;
typedef __attribute__((ext_vector_type(4))) float f32x4;

__device__ inline short f2bf(float f) {
  __hip_bfloat16 h = __float2bfloat16(f);
  return __builtin_bit_cast(short, h);
}

__device__ inline void glds16(const short* src, short* dst) {
  __builtin_amdgcn_global_load_lds(
      (const __attribute__((address_space(1))) unsigned int*)src,
      (__attribute__((address_space(3))) unsigned int*)dst, 16, 0, 0);
}

// ws layout (float offsets)
//   table : 512*784          @ 0        (401408)
//   pn2   : 512              @ 401408
//   idxg  : 131072 (int)     @ 401920
//   part1 : 2048             @ 532992
//   partR : 2048             @ 535040
//   W1T   : 448*800 bf16     @ 537088   (179200 floats)
//   W2T   : 32*416 bf16      @ 716288   (6656 floats)
//   M2P   : 512*32 bf16      @ 722944   (8192 floats)
#define WS_PN2   401408
#define WS_IDX   401920
#define WS_P1    532992
#define WS_PR    535040
#define WS_W1T   537088
#define WS_W2T   716288
#define WS_M2P   722944

// ---------------------------------------------------------------------------
// Decoder table: x_rec_table[k] = relu(prior[k]@W3+b3)@W4 + b4 ; pn2[k]
// ---------------------------------------------------------------------------
__global__ __launch_bounds__(256) void precompute_kernel(
    const float* __restrict__ W3, const float* __restrict__ b3,
    const float* __restrict__ W4, const float* __restrict__ b4,
    const float* __restrict__ prior,
    float* __restrict__ table, float* __restrict__ pn2) {
  __shared__ float ps[D_SZ];
  __shared__ float h2s[H_SZ];
  const int k = blockIdx.x;
  const int t = threadIdx.x;
  if (t < D_SZ) ps[t] = prior[k * D_SZ + t];
  __syncthreads();
  for (int j = t; j < H_SZ; j += 256) {
    float acc = b3[j];
    #pragma unroll
    for (int d = 0; d < D_SZ; ++d) acc += ps[d] * W3[d * H_SZ + j];
    h2s[j] = fmaxf(acc, 0.f);
  }
  if (t == 0) {
    float s = 0.f;
    #pragma unroll
    for (int d = 0; d < D_SZ; ++d) s += ps[d] * ps[d];
    pn2[k] = s;
  }
  __syncthreads();
  for (int f = t; f < F_SZ; f += 256) {
    float acc = b4[f];
    for (int j = 0; j < H_SZ; ++j) acc += h2s[j] * W4[j * F_SZ + f];
    table[(size_t)k * F_SZ + f] = acc;
  }
}

// ---------------------------------------------------------------------------
// W1T[c][k] = bf16(W1[k][c]), [448][800], zero-padded. LDS-tiled transpose.
// ---------------------------------------------------------------------------
__global__ __launch_bounds__(256) void w1t_kernel(const float* __restrict__ W1,
                                                  short* __restrict__ W1T) {
  __shared__ float tile[64][65];
  const int k0 = blockIdx.x * 64;
  const int c0 = blockIdx.y * 64;
  const int t = threadIdx.x;
  for (int i = t; i < 4096; i += 256) {
    const int kk = i >> 6, cc = i & 63;
    const int k = k0 + kk, c = c0 + cc;
    tile[kk][cc] = (k < F_SZ && c < H_SZ) ? W1[(size_t)k * H_SZ + c] : 0.f;
  }
  __syncthreads();
  for (int i = t; i < 4096; i += 256) {
    const int cc = i >> 6, kk = i & 63;
    const int k = k0 + kk, c = c0 + cc;
    if (k < 800) W1T[(size_t)c * 800 + k] = f2bf(tile[kk][cc]);
  }
}

// ---------------------------------------------------------------------------
// W2T[d][j] = bf16(W2[j][d]) [32][416] ; M2P[c][d] = bf16(-2*prior[c][d]) [512][32]
// ---------------------------------------------------------------------------
__global__ __launch_bounds__(256) void prep2_kernel(
    const float* __restrict__ W2, const float* __restrict__ prior,
    short* __restrict__ W2T, short* __restrict__ M2P) {
  const int i = blockIdx.x * 256 + threadIdx.x;
  if (i < 32 * 416) {
    const int d = i / 416, j = i % 416;
    W2T[i] = f2bf((d < D_SZ && j < H_SZ) ? W2[(size_t)j * D_SZ + d] : 0.f);
  }
  if (i < K_SZ * 32) {
    const int c = i / 32, dd = i % 32;
    M2P[i] = f2bf((dd < D_SZ) ? -2.f * prior[(size_t)c * D_SZ + dd] : 0.f);
  }
}

// ---------------------------------------------------------------------------
// Fused encoder (MFMA): h = relu(X@W1+b1) -> z = h@W2+b2 -> argmin dist -> loss1
// BM=64 rows/block, 256 threads (4 waves), N padded to 448, K padded to 800.
// ---------------------------------------------------------------------------
union WH {
  short Ws[2][448 * 32];  // staged W1T chunk, double-buffered (phys swizzled)
  short hs[64 * 424];     // bf16 h tile (odd granule stride 53 -> 2-way reads)
};

__device__ inline int swz4(int r) { return (r & 3) ^ ((r >> 2) & 3); }

__global__ __launch_bounds__(256) void encoder_kernel(
    const float* __restrict__ X, const short* __restrict__ W1T,
    const float* __restrict__ b1, const short* __restrict__ W2T,
    const float* __restrict__ b2, const short* __restrict__ M2P,
    const float* __restrict__ prior, const float* __restrict__ pn2,
    int* __restrict__ idxg, float* __restrict__ partial1) {
  __shared__ short Xs[2][64][32];   // bf16 X tile, granule-swizzled
  __shared__ WH wh;
  __shared__ short zs[64][32];      // bf16 z, granule-swizzled
  __shared__ float pn2s[K_SZ];
  __shared__ float red16[4];

  const int t = threadIdx.x;
  const int w = t >> 6;       // wave 0..3 (N-split in GEMM1, M-split in ph2/3)
  const int l = t & 63;
  const int row0 = blockIdx.x * 64;

  f32x4 acc[4][7];
  #pragma unroll
  for (int mt = 0; mt < 4; ++mt)
    #pragma unroll
    for (int nt = 0; nt < 7; ++nt) acc[mt][nt] = (f32x4){0.f, 0.f, 0.f, 0.f};

  // ---- prologue: stage tile 0 + pn2 ----
  for (int i = t; i < K_SZ; i += 256) pn2s[i] = pn2[i];
  {
    const int r = t >> 2, g = t & 3;
    const int kg = 8 * g;
    const float4 xa = *(const float4*)&X[(size_t)(row0 + r) * F_SZ + kg];
    const float4 xb = *(const float4*)&X[(size_t)(row0 + r) * F_SZ + kg + 4];
    short8v pk;
    pk[0] = f2bf(xa.x); pk[1] = f2bf(xa.y); pk[2] = f2bf(xa.z); pk[3] = f2bf(xa.w);
    pk[4] = f2bf(xb.x); pk[5] = f2bf(xb.y); pk[6] = f2bf(xb.z); pk[7] = f2bf(xb.w);
    const int gw = g ^ swz4(r);
    *(short8v*)&Xs[0][r][gw * 8] = pk;
    for (int ci = w; ci < 28; ci += 4) {
      const int c = ci * 16 + (l >> 2);
      const int tt = l & 3;
      const int srcg = tt ^ swz4(c);
      glds16(W1T + (size_t)c * 800 + 8 * srcg, &wh.Ws[0][ci * 512]);
    }
  }
  __syncthreads();

  // ---- GEMM1 main loop: 25 K-steps of 32, double-buffered ----
  for (int ks = 0; ks < 25; ++ks) {
    const int cur = ks & 1, nxt = cur ^ 1;
    float4 xa = {0.f, 0.f, 0.f, 0.f}, xb = {0.f, 0.f, 0.f, 0.f};
    if (ks < 24) {
      const int k0n = (ks + 1) * 32;
      const int kg = k0n + 8 * (t & 3);
      if (kg < F_SZ) {
        const float* xp = &X[(size_t)(row0 + (t >> 2)) * F_SZ + kg];
        xa = *(const float4*)xp;
        xb = *(const float4*)(xp + 4);
      }
      for (int ci = w; ci < 28; ci += 4) {
        const int c = ci * 16 + (l >> 2);
        const int tt = l & 3;
        const int srcg = tt ^ swz4(c);
        glds16(W1T + (size_t)c * 800 + k0n + 8 * srcg, &wh.Ws[nxt][ci * 512]);
      }
    }
    // compute current tile
    short8v afr[4];
    #pragma unroll
    for (int mt = 0; mt < 4; ++mt) {
      const int row = mt * 16 + (l & 15);
      const int g2 = (l >> 4) ^ swz4(row);
      afr[mt] = *(const short8v*)&Xs[cur][row][g2 * 8];
    }
    #pragma unroll
    for (int nt = 0; nt < 7; ++nt) {
      const int c = w * 112 + nt * 16 + (l & 15);
      const int tg = (l >> 4) ^ swz4(c);
      const short8v bfr = *(const short8v*)&wh.Ws[cur][c * 32 + tg * 8];
      #pragma unroll
      for (int mt = 0; mt < 4; ++mt)
        acc[mt][nt] = __builtin_amdgcn_mfma_f32_16x16x32_bf16(afr[mt], bfr, acc[mt][nt], 0, 0, 0);
    }
    if (ks < 24) {
      short8v pk;
      pk[0] = f2bf(xa.x); pk[1] = f2bf(xa.y); pk[2] = f2bf(xa.z); pk[3] = f2bf(xa.w);
      pk[4] = f2bf(xb.x); pk[5] = f2bf(xb.y); pk[6] = f2bf(xb.z); pk[7] = f2bf(xb.w);
      const int r = t >> 2;
      const int gw = (t & 3) ^ swz4(r);
      *(short8v*)&Xs[nxt][r][gw * 8] = pk;
    }
    __syncthreads();
  }

  // ---- bias+relu, write h tile (bf16) into hs (unions over Ws) ----
  #pragma unroll
  for (int nt = 0; nt < 7; ++nt) {
    const int c = w * 112 + nt * 16 + (l & 15);
    const float b1v = (c < H_SZ) ? b1[c] : 0.f;
    if (c < 416) {
      #pragma unroll
      for (int mt = 0; mt < 4; ++mt)
        #pragma unroll
        for (int rg = 0; rg < 4; ++rg) {
          const int row = mt * 16 + 4 * (l >> 4) + rg;
          wh.hs[row * 424 + c] = f2bf(fmaxf(acc[mt][nt][rg] + b1v, 0.f));
        }
    }
  }
  __syncthreads();

  // ---- phase 2: z = h@W2 + b2 (each wave: its 16 rows) ----
  f32x4 zacc[2];
  #pragma unroll
  for (int nt = 0; nt < 2; ++nt) {
    const int c = nt * 16 + (l & 15);
    const float b2v = (c < D_SZ) ? b2[c] : 0.f;
    zacc[nt] = (f32x4){b2v, b2v, b2v, b2v};
  }
  {
    const int row = w * 16 + (l & 15);
    #pragma unroll
    for (int ks2 = 0; ks2 < 13; ++ks2) {
      const int u = 4 * ks2 + (l >> 4);
      const short8v af = *(const short8v*)&wh.hs[row * 424 + u * 8];
      #pragma unroll
      for (int nt = 0; nt < 2; ++nt) {
        const int c = nt * 16 + (l & 15);
        const short8v bf = *(const short8v*)&W2T[c * 416 + ks2 * 32 + 8 * (l >> 4)];
        zacc[nt] = __builtin_amdgcn_mfma_f32_16x16x32_bf16(af, bf, zacc[nt], 0, 0, 0);
      }
    }
  }

  // zn2 per C-row (rows 4*(l>>4)+rg of this wave's 16)
  float zn2r[4];
  #pragma unroll
  for (int rg = 0; rg < 4; ++rg) {
    float s = zacc[0][rg] * zacc[0][rg] + zacc[1][rg] * zacc[1][rg];
    s += __shfl_xor(s, 1); s += __shfl_xor(s, 2);
    s += __shfl_xor(s, 4); s += __shfl_xor(s, 8);
    zn2r[rg] = s;
  }

  // write z (bf16) for phase-3 A-fragments
  #pragma unroll
  for (int nt = 0; nt < 2; ++nt)
    #pragma unroll
    for (int rg = 0; rg < 4; ++rg) {
      const int row = w * 16 + 4 * (l >> 4) + rg;
      const int c = nt * 16 + (l & 15);
      const int sg = (c >> 3) ^ swz4(row);
      zs[row][sg * 8 + (c & 7)] = f2bf(zacc[nt][rg]);
    }
  __syncthreads();

  // ---- phase 3: distances d = ||z||^2 - 2 z.p + ||p||^2 via MFMA, argmin ----
  const int rowA = w * 16 + (l & 15);
  const int gA = (l >> 4) ^ swz4(rowA);
  const short8v zf = *(const short8v*)&zs[rowA][gA * 8];
  float bv[4] = {3.4e38f, 3.4e38f, 3.4e38f, 3.4e38f};
  int bi[4] = {0, 0, 0, 0};
  for (int nt = 0; nt < 32; ++nt) {
    const int code = nt * 16 + (l & 15);
    const short8v pf = *(const short8v*)&M2P[code * 32 + 8 * (l >> 4)];
    f32x4 dacc = (f32x4){zn2r[0], zn2r[1], zn2r[2], zn2r[3]};
    dacc = __builtin_amdgcn_mfma_f32_16x16x32_bf16(zf, pf, dacc, 0, 0, 0);
    const float pn = pn2s[code];
    #pragma unroll
    for (int rg = 0; rg < 4; ++rg) {
      const float dv = fmaxf(dacc[rg] + pn, 0.f);
      if (dv < bv[rg]) { bv[rg] = dv; bi[rg] = code; }  // ascending code: first-min
    }
  }
  #pragma unroll
  for (int rg = 0; rg < 4; ++rg) {
    float v = bv[rg]; int ii = bi[rg];
    #pragma unroll
    for (int m = 1; m <= 8; m <<= 1) {
      const float ov = __shfl_xor(v, m);
      const int oi = __shfl_xor(ii, m);
      if (ov < v || (ov == v && oi < ii)) { v = ov; ii = oi; }
    }
    bv[rg] = v; bi[rg] = ii;
  }
  if ((l & 15) == 0) {
    #pragma unroll
    for (int rg = 0; rg < 4; ++rg)
      idxg[row0 + w * 16 + 4 * (l >> 4) + rg] = bi[rg];
  }

  // ---- loss_1 partial in f32 from z accumulators ----
  float lsum = 0.f;
  #pragma unroll
  for (int rg = 0; rg < 4; ++rg) {
    const int code = bi[rg];
    const int c0 = l & 15, c1 = 16 + (l & 15);
    const float p0 = prior[(size_t)code * D_SZ + c0];
    const float d0 = zacc[0][rg] - p0;
    lsum += d0 * d0;
    if (c1 < D_SZ) {
      const float p1 = prior[(size_t)code * D_SZ + c1];
      const float d1 = zacc[1][rg] - p1;
      lsum += d1 * d1;
    }
  }
  #pragma unroll
  for (int m = 1; m <= 32; m <<= 1) lsum += __shfl_xor(lsum, m);
  if (l == 0) red16[w] = lsum;
  __syncthreads();
  if (t == 0) partial1[blockIdx.x] = red16[0] + red16[1] + red16[2] + red16[3];
}

// ---------------------------------------------------------------------------
// loss_rec: sum over rows of ||x - table[idx]||^2
// ---------------------------------------------------------------------------
#define R_BLOCKS 2048
#define R_ROWS (B_SZ / R_BLOCKS)  // 64

__global__ __launch_bounds__(256) void rec_kernel(
    const float* __restrict__ X, const float* __restrict__ table,
    const int* __restrict__ idxg, float* __restrict__ partialR) {
  const int t = threadIdx.x;
  const int row0 = blockIdx.x * R_ROWS;
  float acc = 0.f;
  for (int i = t; i < R_ROWS * 196; i += 256) {
    const int rr = i / 196;
    const int f4 = i % 196;
    const int r = row0 + rr;
    const int k = idxg[r];
    const float4 xv = *reinterpret_cast<const float4*>(&X[(size_t)r * F_SZ + f4 * 4]);
    const float4 tv = *reinterpret_cast<const float4*>(&table[(size_t)k * F_SZ + f4 * 4]);
    const float d0 = xv.x - tv.x, d1 = xv.y - tv.y, d2 = xv.z - tv.z, d3 = xv.w - tv.w;
    acc += d0 * d0 + d1 * d1 + d2 * d2 + d3 * d3;
  }
  float v = acc;
  for (int off = 32; off > 0; off >>= 1) v += __shfl_down(v, off);
  __shared__ float rs[4];
  if ((t & 63) == 0) rs[t >> 6] = v;
  __syncthreads();
  if (t == 0) partialR[blockIdx.x] = rs[0] + rs[1] + rs[2] + rs[3];
}

// ---------------------------------------------------------------------------
// Final: loss = (0.625*s1 + srec)/B
// ---------------------------------------------------------------------------
__global__ __launch_bounds__(256) void final_kernel(
    const float* __restrict__ partial1, const float* __restrict__ partialR,
    float* __restrict__ out) {
  __shared__ float s1s[256], srs[256];
  const int t = threadIdx.x;
  float s1 = 0.f, sr = 0.f;
  for (int i = t; i < 2048; i += 256) s1 += partial1[i];
  for (int i = t; i < 2048; i += 256) sr += partialR[i];
  s1s[t] = s1; srs[t] = sr;
  __syncthreads();
  for (int off = 128; off > 0; off >>= 1) {
    if (t < off) { s1s[t] += s1s[t + off]; srs[t] += srs[t + off]; }
    __syncthreads();
  }
  if (t == 0) out[0] = (0.625f * s1s[0] + srs[0]) * (1.0f / (float)B_SZ);
}

extern "C" void kernel_launch(void* const* d_in, const int* in_sizes, int n_in,
                              void* d_out, int out_size, void* d_ws, size_t ws_size,
                              hipStream_t stream) {
  const float* X     = (const float*)d_in[0];
  const float* W1    = (const float*)d_in[1];
  const float* b1    = (const float*)d_in[2];
  const float* W2    = (const float*)d_in[3];
  const float* b2    = (const float*)d_in[4];
  const float* W3    = (const float*)d_in[5];
  const float* b3    = (const float*)d_in[6];
  const float* W4    = (const float*)d_in[7];
  const float* b4    = (const float*)d_in[8];
  const float* prior = (const float*)d_in[9];

  float* wsf   = (float*)d_ws;
  float* table = wsf;
  float* pn2   = wsf + WS_PN2;
  int*   idxg  = (int*)(wsf + WS_IDX);
  float* part1 = wsf + WS_P1;
  float* partR = wsf + WS_PR;
  short* W1T   = (short*)(wsf + WS_W1T);
  short* W2T   = (short*)(wsf + WS_W2T);
  short* M2P   = (short*)(wsf + WS_M2P);
  float* out   = (float*)d_out;

  precompute_kernel<<<dim3(K_SZ), dim3(256), 0, stream>>>(W3, b3, W4, b4, prior, table, pn2);
  w1t_kernel<<<dim3(13, 7), dim3(256), 0, stream>>>(W1, W1T);
  prep2_kernel<<<dim3(64), dim3(256), 0, stream>>>(W2, prior, W2T, M2P);
  encoder_kernel<<<dim3(B_SZ / 64), dim3(256), 0, stream>>>(X, W1T, b1, W2T, b2, M2P, prior, pn2, idxg, part1);
  rec_kernel<<<dim3(R_BLOCKS), dim3(256), 0, stream>>>(X, table, idxg, partR);
  final_kernel<<<dim3(1), dim3(256), 0, stream>>>(part1, partR, out);
}

// Round 3
// 361.491 us; speedup vs baseline: 11.9680x; 1.0812x over previous
//
#include <hip/hip_runtime.h>
#include <hip/hip_bf16.h>

// Problem sizes (fixed)
#define B_SZ 131072
#define F_SZ 784
#define H_SZ 392
#define D_SZ 28
#define K_SZ 512
#define HSTR 424   // hs row stride in shorts (8-multiple: keeps b128 alignment)

typedef __attribute__((ext_vector_type(8))) short short8v;
typedef __attribute__((ext_vector_type(4))) float f32x4;

__device__ inline short f2bf(float f) {
  __hip_bfloat16 h = __float2bfloat16(f);
  return __builtin_bit_cast(short, h);
}

__device__ inline void glds16(const short* src, short* dst) {
  __builtin_amdgcn_global_load_lds(
      (const __attribute__((address_space(1))) unsigned int*)src,
      (__attribute__((address_space(3))) unsigned int*)dst, 16, 0, 0);
}

__device__ inline int swz4(int r) { return (r & 3) ^ ((r >> 2) & 3); }

// ws layout (float offsets) — kept from round 2
#define WS_PN2   401408
#define WS_P1    532992
#define WS_PR    535040
#define WS_W1T   537088
#define WS_W2T   716288
#define WS_M2P   722944

// ---------------------------------------------------------------------------
// Decoder table: x_rec_table[k] = relu(prior[k]@W3+b3)@W4 + b4 ; pn2[k]
// ---------------------------------------------------------------------------
__global__ __launch_bounds__(256) void precompute_kernel(
    const float* __restrict__ W3, const float* __restrict__ b3,
    const float* __restrict__ W4, const float* __restrict__ b4,
    const float* __restrict__ prior,
    float* __restrict__ table, float* __restrict__ pn2) {
  __shared__ float ps[D_SZ];
  __shared__ float h2s[H_SZ];
  const int k = blockIdx.x;
  const int t = threadIdx.x;
  if (t < D_SZ) ps[t] = prior[k * D_SZ + t];
  __syncthreads();
  for (int j = t; j < H_SZ; j += 256) {
    float acc = b3[j];
    #pragma unroll
    for (int d = 0; d < D_SZ; ++d) acc += ps[d] * W3[d * H_SZ + j];
    h2s[j] = fmaxf(acc, 0.f);
  }
  if (t == 0) {
    float s = 0.f;
    #pragma unroll
    for (int d = 0; d < D_SZ; ++d) s += ps[d] * ps[d];
    pn2[k] = s;
  }
  __syncthreads();
  for (int f = t; f < F_SZ; f += 256) {
    float acc = b4[f];
    for (int j = 0; j < H_SZ; ++j) acc += h2s[j] * W4[j * F_SZ + f];
    table[(size_t)k * F_SZ + f] = acc;
  }
}

// ---------------------------------------------------------------------------
// W1T[c][k] = bf16(W1[k][c]), [448][800], zero-padded. LDS-tiled transpose.
// ---------------------------------------------------------------------------
__global__ __launch_bounds__(256) void w1t_kernel(const float* __restrict__ W1,
                                                  short* __restrict__ W1T) {
  __shared__ float tile[64][65];
  const int k0 = blockIdx.x * 64;
  const int c0 = blockIdx.y * 64;
  const int t = threadIdx.x;
  for (int i = t; i < 4096; i += 256) {
    const int kk = i >> 6, cc = i & 63;
    const int k = k0 + kk, c = c0 + cc;
    tile[kk][cc] = (k < F_SZ && c < H_SZ) ? W1[(size_t)k * H_SZ + c] : 0.f;
  }
  __syncthreads();
  for (int i = t; i < 4096; i += 256) {
    const int cc = i >> 6, kk = i & 63;
    const int k = k0 + kk, c = c0 + cc;
    if (k < 800) W1T[(size_t)c * 800 + k] = f2bf(tile[kk][cc]);
  }
}

// ---------------------------------------------------------------------------
// W2T[d][j] = bf16(W2[j][d]) [32][416] ; M2P[c][d] = bf16(-2*prior[c][d]) [512][32]
// ---------------------------------------------------------------------------
__global__ __launch_bounds__(256) void prep2_kernel(
    const float* __restrict__ W2, const float* __restrict__ prior,
    short* __restrict__ W2T, short* __restrict__ M2P) {
  const int i = blockIdx.x * 256 + threadIdx.x;
  if (i < 32 * 416) {
    const int d = i / 416, j = i % 416;
    W2T[i] = f2bf((d < D_SZ && j < H_SZ) ? W2[(size_t)j * D_SZ + d] : 0.f);
  }
  if (i < K_SZ * 32) {
    const int c = i / 32, dd = i % 32;
    M2P[i] = f2bf((dd < D_SZ) ? -2.f * prior[(size_t)c * D_SZ + dd] : 0.f);
  }
}

// ---------------------------------------------------------------------------
// Fused encoder (MFMA, counted-vmcnt pipeline):
//   h = relu(X@W1+b1) -> z = h@W2+b2 -> argmin dist -> loss1 -> fused loss_rec
// BM=64 rows/block, 256 threads (4 waves). N padded 448, K padded 800.
// Pipeline invariant (per wave, per step ks):
//   entering step: outstanding VMEM = [X(ks+1) pair] (2)
//   issue W(ks+1) glds x7, then X(ks+2) pair  -> queue [X+1:2, W+1:7, X+2:2]
//   MFMA on Xs[ks%3], Ws[ks&1]; ds_write X(ks+1) tile (regs from prev step)
//   s_waitcnt vmcnt(2)  => X(ks+1) and W(ks+1) landed; X(ks+2) stays in flight
//   raw s_barrier (no drain-0 in main loop)
// ---------------------------------------------------------------------------
union WH {
  short Ws[2][448 * 32];  // staged W1T chunk, double-buffered (57,344 B)
  short hs[64 * HSTR];    // bf16 h tile (54,272 B)
};

__global__ __launch_bounds__(256, 2) void encoder_kernel(
    const float* __restrict__ X, const short* __restrict__ W1T,
    const float* __restrict__ b1, const short* __restrict__ W2T,
    const float* __restrict__ b2, const short* __restrict__ M2P,
    const float* __restrict__ prior, const float* __restrict__ pn2,
    const float* __restrict__ table,
    float* __restrict__ partial1, float* __restrict__ partialR) {
  __shared__ short Xs[3][64][32];   // bf16 X tiles, ring-3, granule-swizzled
  __shared__ WH wh;
  __shared__ short zs[64][32];      // bf16 z, granule-swizzled
  __shared__ float pn2s[K_SZ];
  __shared__ float red1[4], redR[4];

  const int t = threadIdx.x;
  const int w = t >> 6;       // wave 0..3 (N-split in GEMM1, M-split in tail)
  const int l = t & 63;
  const int row0 = blockIdx.x * 64;

  f32x4 acc[4][7];
  #pragma unroll
  for (int mt = 0; mt < 4; ++mt)
    #pragma unroll
    for (int nt = 0; nt < 7; ++nt) acc[mt][nt] = (f32x4){0.f, 0.f, 0.f, 0.f};

  // b1 preload (keeps main loop free of stray VMEM -> exact vmcnt immediates)
  float b1v[7];
  #pragma unroll
  for (int nt = 0; nt < 7; ++nt) {
    const int c = w * 112 + nt * 16 + (l & 15);
    b1v[nt] = (c < H_SZ) ? b1[c] : 0.f;
  }

  // ---- prologue: stage W(0), Xs[0]; keep X(1) in regs; full drain once ----
  float4 xa1, xb1;
  for (int i = t; i < K_SZ; i += 256) pn2s[i] = pn2[i];
  {
    for (int ci = w; ci < 28; ci += 4) {
      const int c = ci * 16 + (l >> 2);
      const int srcg = (l & 3) ^ swz4(c);
      glds16(W1T + (size_t)c * 800 + 8 * srcg, &wh.Ws[0][ci * 512]);
    }
    const int r = t >> 2;
    const int kg = 8 * (t & 3);
    const float* xp = &X[(size_t)(row0 + r) * F_SZ + kg];
    const float4 a0 = *(const float4*)xp;
    const float4 b0 = *(const float4*)(xp + 4);
    xa1 = *(const float4*)(xp + 32);     // tile 1 (cols 32..63)
    xb1 = *(const float4*)(xp + 36);
    short8v pk;
    pk[0] = f2bf(a0.x); pk[1] = f2bf(a0.y); pk[2] = f2bf(a0.z); pk[3] = f2bf(a0.w);
    pk[4] = f2bf(b0.x); pk[5] = f2bf(b0.y); pk[6] = f2bf(b0.z); pk[7] = f2bf(b0.w);
    *(short8v*)&Xs[0][r][((t & 3) ^ swz4(r)) * 8] = pk;
  }
  __syncthreads();   // drains everything once; loop invariant: queue empty

  // ---- GEMM1 main loop: 25 K-steps of 32 ----
  for (int ks = 0; ks < 25; ++ks) {
    const int xb_cur = ks % 3;
    const int wb_cur = ks & 1;
    float4 xa2 = {0.f, 0.f, 0.f, 0.f}, xb2 = {0.f, 0.f, 0.f, 0.f};
    if (ks < 24) {
      const int k0n = (ks + 1) * 32;
      for (int ci = w; ci < 28; ci += 4) {
        const int c = ci * 16 + (l >> 2);
        const int srcg = (l & 3) ^ swz4(c);
        glds16(W1T + (size_t)c * 800 + k0n + 8 * srcg, &wh.Ws[wb_cur ^ 1][ci * 512]);
      }
      __builtin_amdgcn_sched_barrier(0);   // pin: W glds issue before X loads
      const int kt = (ks + 2 <= 24) ? (ks + 2) : 24;  // clamp: uniform VMEM count
      const int kg = kt * 32 + 8 * (t & 3);
      if (kg < F_SZ) {
        const float* xp = &X[(size_t)(row0 + (t >> 2)) * F_SZ + kg];
        xa2 = *(const float4*)xp;
        xb2 = *(const float4*)(xp + 4);
      }
      __builtin_amdgcn_sched_barrier(0);
    }
    // compute current tile
    short8v afr[4];
    #pragma unroll
    for (int mt = 0; mt < 4; ++mt) {
      const int row = mt * 16 + (l & 15);
      const int g2 = (l >> 4) ^ swz4(row);
      afr[mt] = *(const short8v*)&Xs[xb_cur][row][g2 * 8];
    }
    #pragma unroll
    for (int nt = 0; nt < 7; ++nt) {
      const int c = w * 112 + nt * 16 + (l & 15);
      const int tg = (l >> 4) ^ swz4(c);
      const short8v bfr = *(const short8v*)&wh.Ws[wb_cur][c * 32 + tg * 8];
      #pragma unroll
      for (int mt = 0; mt < 4; ++mt)
        acc[mt][nt] = __builtin_amdgcn_mfma_f32_16x16x32_bf16(afr[mt], bfr, acc[mt][nt], 0, 0, 0);
    }
    if (ks < 24) {
      // write X(ks+1) tile from regs loaded last step
      short8v pk;
      pk[0] = f2bf(xa1.x); pk[1] = f2bf(xa1.y); pk[2] = f2bf(xa1.z); pk[3] = f2bf(xa1.w);
      pk[4] = f2bf(xb1.x); pk[5] = f2bf(xb1.y); pk[6] = f2bf(xb1.z); pk[7] = f2bf(xb1.w);
      const int r = t >> 2;
      *(short8v*)&Xs[(ks + 1) % 3][r][((t & 3) ^ swz4(r)) * 8] = pk;
      xa1 = xa2; xb1 = xb2;
    }
    asm volatile("s_waitcnt vmcnt(2) lgkmcnt(0)" ::: "memory");
    __builtin_amdgcn_s_barrier();
  }
  // keep tail dummy loads alive (uniform vmcnt counts; rule-17 keepalive)
  asm volatile("" :: "v"(xa1.x), "v"(xb1.w));

  // ---- bias+relu, write h tile (bf16) into hs (unions over Ws) ----
  #pragma unroll
  for (int nt = 0; nt < 7; ++nt) {
    const int c = w * 112 + nt * 16 + (l & 15);
    if (c < 416) {
      #pragma unroll
      for (int mt = 0; mt < 4; ++mt)
        #pragma unroll
        for (int rg = 0; rg < 4; ++rg) {
          const int row = mt * 16 + 4 * (l >> 4) + rg;
          wh.hs[row * HSTR + c] = f2bf(fmaxf(acc[mt][nt][rg] + b1v[nt], 0.f));
        }
    }
  }
  __syncthreads();

  // ---- phase 2: z = h@W2 + b2 (each wave: its 16 rows) ----
  f32x4 zacc[2];
  #pragma unroll
  for (int nt = 0; nt < 2; ++nt) {
    const int c = nt * 16 + (l & 15);
    const float b2v = (c < D_SZ) ? b2[c] : 0.f;
    zacc[nt] = (f32x4){b2v, b2v, b2v, b2v};
  }
  {
    const int row = w * 16 + (l & 15);
    #pragma unroll
    for (int ks2 = 0; ks2 < 13; ++ks2) {
      const int u = 4 * ks2 + (l >> 4);
      const short8v af = *(const short8v*)&wh.hs[row * HSTR + u * 8];
      #pragma unroll
      for (int nt = 0; nt < 2; ++nt) {
        const int c = nt * 16 + (l & 15);
        const short8v bf = *(const short8v*)&W2T[c * 416 + ks2 * 32 + 8 * (l >> 4)];
        zacc[nt] = __builtin_amdgcn_mfma_f32_16x16x32_bf16(af, bf, zacc[nt], 0, 0, 0);
      }
    }
  }

  // zn2 per C-row
  float zn2r[4];
  #pragma unroll
  for (int rg = 0; rg < 4; ++rg) {
    float s = zacc[0][rg] * zacc[0][rg] + zacc[1][rg] * zacc[1][rg];
    s += __shfl_xor(s, 1); s += __shfl_xor(s, 2);
    s += __shfl_xor(s, 4); s += __shfl_xor(s, 8);
    zn2r[rg] = s;
  }

  // write z (bf16) for phase-3 A-fragments
  #pragma unroll
  for (int nt = 0; nt < 2; ++nt)
    #pragma unroll
    for (int rg = 0; rg < 4; ++rg) {
      const int row = w * 16 + 4 * (l >> 4) + rg;
      const int c = nt * 16 + (l & 15);
      const int sg = (c >> 3) ^ swz4(row);
      zs[row][sg * 8 + (c & 7)] = f2bf(zacc[nt][rg]);
    }
  __syncthreads();

  // ---- phase 3: d = ||z||^2 - 2 z.p + ||p||^2 via MFMA, argmin ----
  const int rowA = w * 16 + (l & 15);
  const int gA = (l >> 4) ^ swz4(rowA);
  const short8v zf = *(const short8v*)&zs[rowA][gA * 8];
  float bv[4] = {3.4e38f, 3.4e38f, 3.4e38f, 3.4e38f};
  int bi[4] = {0, 0, 0, 0};
  #pragma unroll 8
  for (int nt = 0; nt < 32; ++nt) {
    const int code = nt * 16 + (l & 15);
    const short8v pf = *(const short8v*)&M2P[code * 32 + 8 * (l >> 4)];
    f32x4 dacc = (f32x4){zn2r[0], zn2r[1], zn2r[2], zn2r[3]};
    dacc = __builtin_amdgcn_mfma_f32_16x16x32_bf16(zf, pf, dacc, 0, 0, 0);
    const float pn = pn2s[code];
    #pragma unroll
    for (int rg = 0; rg < 4; ++rg) {
      const float dv = fmaxf(dacc[rg] + pn, 0.f);
      if (dv < bv[rg]) { bv[rg] = dv; bi[rg] = code; }  // ascending code: first-min
    }
  }
  #pragma unroll
  for (int rg = 0; rg < 4; ++rg) {
    float v = bv[rg]; int ii = bi[rg];
    #pragma unroll
    for (int m = 1; m <= 8; m <<= 1) {
      const float ov = __shfl_xor(v, m);
      const int oi = __shfl_xor(ii, m);
      if (ov < v || (ov == v && oi < ii)) { v = ov; ii = oi; }
    }
    bv[rg] = v; bi[rg] = ii;
  }

  // ---- loss_1 partial in f32 from z accumulators ----
  float lsum = 0.f;
  #pragma unroll
  for (int rg = 0; rg < 4; ++rg) {
    const int code = bi[rg];
    const int c0 = l & 15, c1 = 16 + (l & 15);
    const float p0 = prior[(size_t)code * D_SZ + c0];
    const float d0 = zacc[0][rg] - p0;
    lsum += d0 * d0;
    if (c1 < D_SZ) {
      const float p1 = prior[(size_t)code * D_SZ + c1];
      const float d1 = zacc[1][rg] - p1;
      lsum += d1 * d1;
    }
  }

  // ---- fused loss_rec: this wave's 16 rows, Sum ||x - table[idx]||^2 ----
  float racc = 0.f;
  #pragma unroll 4
  for (int rr = 0; rr < 16; ++rr) {
    const int kk = __shfl(bi[rr & 3], (rr >> 2) << 4);  // idx of row rr (all 16 lanes of group hold it)
    const float4* xr4 = (const float4*)&X[(size_t)(row0 + w * 16 + rr) * F_SZ];
    const float4* tr4 = (const float4*)&table[(size_t)kk * F_SZ];
    #pragma unroll
    for (int s = 0; s < 3; ++s) {
      const int i = l + 64 * s;
      const float4 xv = xr4[i], tv = tr4[i];
      const float d0 = xv.x - tv.x, d1 = xv.y - tv.y, d2 = xv.z - tv.z, d3 = xv.w - tv.w;
      racc += d0 * d0 + d1 * d1 + d2 * d2 + d3 * d3;
    }
    if (l < 4) {
      const int i = 192 + l;
      const float4 xv = xr4[i], tv = tr4[i];
      const float d0 = xv.x - tv.x, d1 = xv.y - tv.y, d2 = xv.z - tv.z, d3 = xv.w - tv.w;
      racc += d0 * d0 + d1 * d1 + d2 * d2 + d3 * d3;
    }
  }

  // ---- block reduction for both partials ----
  #pragma unroll
  for (int m = 1; m <= 32; m <<= 1) {
    lsum += __shfl_xor(lsum, m);
    racc += __shfl_xor(racc, m);
  }
  if (l == 0) { red1[w] = lsum; redR[w] = racc; }
  __syncthreads();
  if (t == 0) {
    partial1[blockIdx.x] = red1[0] + red1[1] + red1[2] + red1[3];
    partialR[blockIdx.x] = redR[0] + redR[1] + redR[2] + redR[3];
  }
}

// ---------------------------------------------------------------------------
// Final: loss = (0.625*s1 + srec)/B   (loss_1 == loss_2 forward; 1.25*0.5)
// ---------------------------------------------------------------------------
__global__ __launch_bounds__(256) void final_kernel(
    const float* __restrict__ partial1, const float* __restrict__ partialR,
    float* __restrict__ out) {
  __shared__ float s1s[256], srs[256];
  const int t = threadIdx.x;
  float s1 = 0.f, sr = 0.f;
  for (int i = t; i < 2048; i += 256) s1 += partial1[i];
  for (int i = t; i < 2048; i += 256) sr += partialR[i];
  s1s[t] = s1; srs[t] = sr;
  __syncthreads();
  for (int off = 128; off > 0; off >>= 1) {
    if (t < off) { s1s[t] += s1s[t + off]; srs[t] += srs[t + off]; }
    __syncthreads();
  }
  if (t == 0) out[0] = (0.625f * s1s[0] + srs[0]) * (1.0f / (float)B_SZ);
}

extern "C" void kernel_launch(void* const* d_in, const int* in_sizes, int n_in,
                              void* d_out, int out_size, void* d_ws, size_t ws_size,
                              hipStream_t stream) {
  const float* X     = (const float*)d_in[0];
  const float* W1    = (const float*)d_in[1];
  const float* b1    = (const float*)d_in[2];
  const float* W2    = (const float*)d_in[3];
  const float* b2    = (const float*)d_in[4];
  const float* W3    = (const float*)d_in[5];
  const float* b3    = (const float*)d_in[6];
  const float* W4    = (const float*)d_in[7];
  const float* b4    = (const float*)d_in[8];
  const float* prior = (const float*)d_in[9];

  float* wsf   = (float*)d_ws;
  float* table = wsf;
  float* pn2   = wsf + WS_PN2;
  float* part1 = wsf + WS_P1;
  float* partR = wsf + WS_PR;
  short* W1T   = (short*)(wsf + WS_W1T);
  short* W2T   = (short*)(wsf + WS_W2T);
  short* M2P   = (short*)(wsf + WS_M2P);
  float* out   = (float*)d_out;

  precompute_kernel<<<dim3(K_SZ), dim3(256), 0, stream>>>(W3, b3, W4, b4, prior, table, pn2);
  w1t_kernel<<<dim3(13, 7), dim3(256), 0, stream>>>(W1, W1T);
  prep2_kernel<<<dim3(64), dim3(256), 0, stream>>>(W2, prior, W2T, M2P);
  encoder_kernel<<<dim3(B_SZ / 64), dim3(256), 0, stream>>>(
      X, W1T, b1, W2T, b2, M2P, prior, pn2, table, part1, partR);
  final_kernel<<<dim3(1), dim3(256), 0, stream>>>(part1, partR, out);
}